// Round 2
// baseline (1536.107 us; speedup 1.0000x reference)
//
#include <hip/hip_runtime.h>
#include <cstdint>
#include <cstddef>

// Problem constants (from reference setup)
#define SEQ    2048
#define HID    1024
#define NBAT   64
#define NSEG   4
#define NNODE  7
#define TCHUNK 128   // tokens per pooling task chunk (SEQ/TCHUNK = 16 chunks)
#define NBLK   512   // persistent grid: 2 blocks/CU on 256 CUs (co-resident)

#define BM 32
#define BN 64
#define BK 32

__device__ __forceinline__ float gelu_f(float x) {
  // exact erf gelu (jax approximate=False / torch default GELU)
  return 0.5f * x * (1.0f + erff(x * 0.7071067811865476f));
}

// ---------------------------------------------------------------------------
// Device-scope grid barrier (persistent kernel, all NBLK blocks co-resident).
// Monotonic counter (no reset); zeroed by the host-side memset each launch.
// Release: __threadfence() flushes this XCD's L2 to the coherence point.
// Spin uses RELAXED agent-scope loads (no cache-inv per poll, so co-resident
// compute blocks keep their L1/L2); one acquire fence after exit.
// ---------------------------------------------------------------------------
__device__ __forceinline__ void grid_barrier(unsigned* cnt, unsigned target) {
  __syncthreads();
  __threadfence();                       // release (buffer_wbl2 on gfx95x)
  if (threadIdx.x == 0) {
    __hip_atomic_fetch_add(cnt, 1u, __ATOMIC_RELAXED, __HIP_MEMORY_SCOPE_AGENT);
    while (__hip_atomic_load(cnt, __ATOMIC_RELAXED, __HIP_MEMORY_SCOPE_AGENT) < target)
      __builtin_amdgcn_s_sleep(1);
  }
  __syncthreads();
  __threadfence();                       // acquire (buffer_inv): see peers' data
}

// ---------------------------------------------------------------------------
// Stage 0: ragged segment-sum pooling. 1024 (chunk,batch) tasks over NBLK
// blocks (2 tasks each). Atomic partial sums into pooled (zeroed by memset).
// ---------------------------------------------------------------------------
__device__ void pool_stage(const float* __restrict__ states,
                           const int* __restrict__ boundaries,
                           const int* __restrict__ lengths,
                           float* __restrict__ pooled_sum) {
  const int tid = threadIdx.x;
  for (int task = blockIdx.x; task < 1024; task += NBLK) {
    const int tc = task & 15, b = task >> 4;
    const int len = lengths[b];
    int bnd[5];
    bnd[0] = boundaries[b * 4 + 0];
    bnd[1] = boundaries[b * 4 + 1];
    bnd[2] = boundaries[b * 4 + 2];
    bnd[3] = boundaries[b * 4 + 3];
    bnd[4] = len;
    const int clo = tc * TCHUNK, chi = clo + TCHUNK;
    const float4* S = (const float4*)(states + (size_t)b * SEQ * HID);

    #pragma unroll
    for (int s = 0; s < NSEG; ++s) {
      int lo = bnd[s]     > clo ? bnd[s]     : clo;
      int hi = bnd[s + 1] < chi ? bnd[s + 1] : chi;
      if (lo >= hi) continue;                     // block-uniform branch
      float4 acc = make_float4(0.f, 0.f, 0.f, 0.f);
      int t = lo;
      for (; t + 4 <= hi; t += 4) {
        float4 v0 = S[(size_t)(t + 0) * (HID / 4) + tid];
        float4 v1 = S[(size_t)(t + 1) * (HID / 4) + tid];
        float4 v2 = S[(size_t)(t + 2) * (HID / 4) + tid];
        float4 v3 = S[(size_t)(t + 3) * (HID / 4) + tid];
        acc.x += (v0.x + v1.x) + (v2.x + v3.x);
        acc.y += (v0.y + v1.y) + (v2.y + v3.y);
        acc.z += (v0.z + v1.z) + (v2.z + v3.z);
        acc.w += (v0.w + v1.w) + (v2.w + v3.w);
      }
      for (; t < hi; ++t) {
        float4 v = S[(size_t)t * (HID / 4) + tid];
        acc.x += v.x; acc.y += v.y; acc.z += v.z; acc.w += v.w;
      }
      float* dst = pooled_sum + (size_t)(b * NSEG + s) * HID + tid * 4;
      atomicAdd(dst + 0, acc.x);
      atomicAdd(dst + 1, acc.y);
      atomicAdd(dst + 2, acc.z);
      atomicAdd(dst + 3, acc.w);
    }
  }
}

// ---------------------------------------------------------------------------
// Generic split-K GEMM stage inside the persistent kernel.
// Block mapping (XCD-aware): bid -> glo=bid&7, nx=(bid>>3)&15, ghi=bid>>7;
// group g = glo + 8*ghi in [0,32); m-tile = g & (nm-1); z = g >> log2(nm).
// -> XCD(bid)=bid%8 equals g%8, so the 16 n-blocks of one (m,z) A-tile share
//    one XCD's L2 (A partials fetched from LLC once per XCD).
// All stages: 16 n-tiles x nm m-tiles x SPLIT z = 512 blocks, 32 groups.
// AMODE 1: A = pooled row (scaled 1/max(cnt,1))                         (G1)
// AMODE 3: A = gelu(sum_q P[q] + preb)   — prev stage's split-K reduce  (G2,G4,G6)
// AMODE 4: A = leaf value from P2 partials: (sum+b2+dembed)*leaf_ok     (G3)
// AMODE 5: A = node value from P4 partials: (sum+bm2+dembed)*is_int     (G5)
// Output: raw partial sums Cp[z][M][1024].
// ---------------------------------------------------------------------------
template<int AMODE, int SRCS, int NMLOG, int KLOC>
__device__ void gemm_stage(
    float (*As)[BM + 2], float (*Ws)[BN],
    const float* __restrict__ Asrc, const float* __restrict__ W,
    const float* __restrict__ preb, float* __restrict__ Cp,
    int prows, int M,
    const int* __restrict__ boundaries, const int* __restrict__ lengths,
    const int* __restrict__ leaf_order, const int* __restrict__ active,
    const int* __restrict__ is_leaf, const int* __restrict__ depth,
    const int* __restrict__ left_child, const int* __restrict__ right_child,
    const float* __restrict__ dembed, int nodeA, int nodeB)
{
  static_assert(KLOC % BK == 0, "KLOC must be a multiple of BK");
  const int N = 1024;
  const int tid = threadIdx.x;
  const int bid = blockIdx.x;
  const int nx  = (bid >> 3) & 15;
  const int g   = (bid & 7) + ((bid >> 7) << 3);
  const int mi  = g & ((1 << NMLOG) - 1);
  const int z   = g >> NMLOG;
  const int n0  = nx * BN, m0 = mi * BM;
  const int kbeg = z * KLOC;

  const int am = tid >> 3;            // 0..31  A tile row this thread stages
  const int ak = (tid & 7) * 4;       // 0..28  A tile k
  const int wk = tid >> 3;            // 0..31  W tile k
  const int wn = (tid & 7) * 8;       // 0..56  W tile n
  const int rm = (tid >> 4) * 2;      // compute rows
  const int cn = (tid & 15) * 4;      // compute cols

  // ---- per-thread A-row setup (hoisted; applies to the row this thread stages)
  float sc = 1.0f;
  int prow = m0 + am;
  const float* de = dembed;           // dummy default
  if constexpr (AMODE == 1) {
    int m = m0 + am; int b = m >> 2; int s = m & 3;
    int bs  = boundaries[b * 4 + s];
    int bn2 = (s < 3) ? boundaries[b * 4 + s + 1] : lengths[b];
    sc = 1.0f / fmaxf((float)(bn2 - bs), 1.0f);
  } else if constexpr (AMODE == 4) {
    // K-slice lies entirely within one child (KLOC divides 1024)
    int mrow = m0 + am; int nodei = mrow >> 6; int b = mrow & 63;
    int node = nodei ? nodeB : nodeA;
    int cd = (kbeg < 1024) ? left_child[node] : right_child[node];
    int srow = -1;
    #pragma unroll
    for (int s = 0; s < 4; ++s)
      if (leaf_order[b * 4 + s] == cd) srow = s;
    bool ok = false; prow = 0; int dep = 0;
    if (cd >= 0 && srow >= 0) {
      int bs  = boundaries[b * 4 + srow];
      int bn2 = (srow < 3) ? boundaries[b * 4 + srow + 1] : lengths[b];
      ok = (is_leaf[b * NNODE + cd] != 0) && (bn2 - bs > 0);
      prow = b * 4 + srow;
      dep = depth[cd];
    }
    sc = ok ? 1.0f : 0.0f;
    de = dembed + (size_t)dep * 1024;
  } else if constexpr (AMODE == 5) {
    int mrow = m0 + am; int b = mrow & 63;
    int cd = (kbeg < 1024) ? left_child[nodeA] : right_child[nodeA];
    prow = 0; int dep = 0; bool ii = false;
    if (cd >= 1) {
      ii = (active[b * NNODE + cd] != 0) && (is_leaf[b * NNODE + cd] == 0);
      prow = (cd - 1) * 64 + b;       // row in P4 [128][1024]
      dep = depth[cd];
    }
    sc = ii ? 1.0f : 0.0f;
    de = dembed + (size_t)dep * 1024;
  }
  const int hbase = (AMODE == 4 || AMODE == 5) ? (kbeg & 1023) : kbeg;

  float acc[2][4] = {{0.f,0.f,0.f,0.f},{0.f,0.f,0.f,0.f}};
  float4 av[SRCS], bv, dv, wv0, wv1;

  auto issueA = [&](int koff) {
    const int h = hbase + koff;
    #pragma unroll
    for (int q = 0; q < SRCS; ++q)
      av[q] = *(const float4*)(Asrc + ((size_t)q * prows + prow) * 1024 + h);
    if constexpr (AMODE >= 3) bv = *(const float4*)(preb + h);
    if constexpr (AMODE == 4 || AMODE == 5) dv = *(const float4*)(de + h);
  };

  // ---- prefetch tile 0
  issueA(ak);
  wv0 = *(const float4*)(W + (size_t)(kbeg + wk) * N + n0 + wn);
  wv1 = *(const float4*)(W + (size_t)(kbeg + wk) * N + n0 + wn + 4);

  #pragma unroll 1
  for (int k0 = 0; k0 < KLOC; k0 += BK) {
    __syncthreads();                  // readers of previous tile done
    {
      float4 s = av[0];
      #pragma unroll
      for (int q = 1; q < SRCS; ++q) {
        s.x += av[q].x; s.y += av[q].y; s.z += av[q].z; s.w += av[q].w;
      }
      float4 a;
      if constexpr (AMODE == 3) {
        a.x = gelu_f(s.x + bv.x); a.y = gelu_f(s.y + bv.y);
        a.z = gelu_f(s.z + bv.z); a.w = gelu_f(s.w + bv.w);
      } else if constexpr (AMODE == 4 || AMODE == 5) {
        a.x = (s.x + bv.x + dv.x) * sc; a.y = (s.y + bv.y + dv.y) * sc;
        a.z = (s.z + bv.z + dv.z) * sc; a.w = (s.w + bv.w + dv.w) * sc;
      } else {
        a.x = s.x * sc; a.y = s.y * sc; a.z = s.z * sc; a.w = s.w * sc;
      }
      As[ak + 0][am] = a.x;
      As[ak + 1][am] = a.y;
      As[ak + 2][am] = a.z;
      As[ak + 3][am] = a.w;
    }
    *(float4*)&Ws[wk][wn]     = wv0;
    *(float4*)&Ws[wk][wn + 4] = wv1;
    __syncthreads();                  // staging visible

    const int kn = k0 + BK;
    if (kn < KLOC) {                  // issue next tile's loads now
      issueA(kn + ak);
      wv0 = *(const float4*)(W + (size_t)(kbeg + kn + wk) * N + n0 + wn);
      wv1 = *(const float4*)(W + (size_t)(kbeg + kn + wk) * N + n0 + wn + 4);
    }

    #pragma unroll
    for (int kk = 0; kk < BK; ++kk) {
      float2 a2 = *(const float2*)&As[kk][rm];
      float4 w  = *(const float4*)&Ws[kk][cn];
      acc[0][0] += a2.x * w.x; acc[0][1] += a2.x * w.y;
      acc[0][2] += a2.x * w.z; acc[0][3] += a2.x * w.w;
      acc[1][0] += a2.y * w.x; acc[1][1] += a2.y * w.y;
      acc[1][2] += a2.y * w.z; acc[1][3] += a2.y * w.w;
    }
  }

  // ---- write raw partials
  #pragma unroll
  for (int r = 0; r < 2; ++r) {
    const int m = m0 + rm + r;
    *(float4*)(Cp + ((size_t)z * M + m) * 1024 + n0 + cn) =
        make_float4(acc[r][0], acc[r][1], acc[r][2], acc[r][3]);
  }
}

// ---------------------------------------------------------------------------
// The persistent fused kernel: pool -> G1..G6 -> root epilogue, 7 barriers.
// grid 512 x 256, __launch_bounds__(256,2) => 2 blocks/CU guaranteed
// co-resident (VGPR cap 256, LDS 12.5 KB/block).
// ---------------------------------------------------------------------------
__global__ __launch_bounds__(256, 2) void fused_kernel(
    const float* __restrict__ states,
    const int* __restrict__ boundaries, const int* __restrict__ lengths,
    const int* __restrict__ leaf_order, const int* __restrict__ active,
    const int* __restrict__ is_leaf, const int* __restrict__ left_child,
    const int* __restrict__ right_child, const int* __restrict__ depth,
    const float* __restrict__ W1, const float* __restrict__ b1,
    const float* __restrict__ W2, const float* __restrict__ b2,
    const float* __restrict__ Wm1, const float* __restrict__ bm1,
    const float* __restrict__ Wm2, const float* __restrict__ bm2,
    const float* __restrict__ dembed, const float* __restrict__ sembed,
    float* __restrict__ pooled,
    float* __restrict__ P1, float* __restrict__ P2, float* __restrict__ P3,
    float* __restrict__ P4, float* __restrict__ P5, float* __restrict__ P6,
    unsigned* __restrict__ barcnt, float* __restrict__ out)
{
  __shared__ float As[BK][BM + 2];
  __shared__ float Ws[BK][BN];

  // stage 0: pooling (atomic partial sums into zeroed `pooled`)
  pool_stage(states, boundaries, lengths, pooled);
  grid_barrier(barcnt, 1 * NBLK);

  // G1: P1[4] = (pooled/cnt) @ W1           M=256 K=1024 KLOC=256
  gemm_stage<1, 1, 3, 256>(As, Ws, pooled, W1, nullptr, P1, 256, 256,
      boundaries, lengths, leaf_order, active, is_leaf, depth,
      left_child, right_child, dembed, -1, -1);
  grid_barrier(barcnt, 2 * NBLK);

  // G2: P2[4] = gelu(sum P1 + b1) @ W2      M=256 K=1024 KLOC=256
  gemm_stage<3, 4, 3, 256>(As, Ws, P1, W2, b1, P2, 256, 256,
      boundaries, lengths, leaf_order, active, is_leaf, depth,
      left_child, right_child, dembed, -1, -1);
  grid_barrier(barcnt, 3 * NBLK);

  // G3: P3[8] = concat(leafval(lc), leafval(rc)) @ Wm1  (nodes 1,2)
  //     leafval from P2 partials (+b2+dembed, masked)   M=128 K=2048 KLOC=256
  gemm_stage<4, 4, 2, 256>(As, Ws, P2, Wm1, b2, P3, 256, 128,
      boundaries, lengths, leaf_order, active, is_leaf, depth,
      left_child, right_child, dembed, 1, 2);
  grid_barrier(barcnt, 4 * NBLK);

  // G4: P4[8] = gelu(sum P3 + bm1) @ Wm2    M=128 K=1024 KLOC=128
  gemm_stage<3, 8, 2, 128>(As, Ws, P3, Wm2, bm1, P4, 128, 128,
      boundaries, lengths, leaf_order, active, is_leaf, depth,
      left_child, right_child, dembed, -1, -1);
  grid_barrier(barcnt, 5 * NBLK);

  // G5: P5[16] = concat(nodeval(1), nodeval(2)) @ Wm1   (root)
  //     nodeval from P4 partials (+bm2+dembed, masked)  M=64 K=2048 KLOC=128
  gemm_stage<5, 8, 1, 128>(As, Ws, P4, Wm1, bm2, P5, 128, 64,
      boundaries, lengths, leaf_order, active, is_leaf, depth,
      left_child, right_child, dembed, 0, 0);
  grid_barrier(barcnt, 6 * NBLK);

  // G6: P6[16] = gelu(sum P5 + bm1) @ Wm2   M=64 K=1024 KLOC=64
  gemm_stage<3, 16, 1, 64>(As, Ws, P5, Wm2, bm1, P6, 64, 64,
      boundaries, lengths, leaf_order, active, is_leaf, depth,
      left_child, right_child, dembed, -1, -1);
  grid_barrier(barcnt, 7 * NBLK);

  // E3: out = (sum P6 + bm2 + dembed[0]) * is_int + sembed[hash]
  if (blockIdx.x < 64) {
    const int b = blockIdx.x;
    const int n = threadIdx.x * 4;
    float4 x = *(const float4*)(P6 + (size_t)b * 1024 + n);
    #pragma unroll
    for (int q = 1; q < 16; ++q) {
      float4 p = *(const float4*)(P6 + ((size_t)q * 64 + b) * 1024 + n);
      x.x += p.x; x.y += p.y; x.z += p.z; x.w += p.w;
    }
    x.x += bm2[n + 0]; x.y += bm2[n + 1]; x.z += bm2[n + 2]; x.w += bm2[n + 3];
    bool ii = (active[b * NNODE + 0] != 0) && (is_leaf[b * NNODE + 0] == 0);
    const float* de = dembed + (size_t)depth[0] * 1024 + n;
    float sc = ii ? 1.0f : 0.0f;
    long long h = 0, w = 1;
    #pragma unroll
    for (int i = 0; i < NNODE; ++i) {
      long long p = (long long)active[b * NNODE + i] * 2
                  + (long long)is_leaf[b * NNODE + i];
      h += p * w;
      w *= 31;
    }
    long long a = h < 0 ? -h : h;
    int sid = (int)(a % 256);
    const float* se = sembed + (size_t)sid * 1024 + n;
    x.x = (x.x + de[0]) * sc + se[0];
    x.y = (x.y + de[1]) * sc + se[1];
    x.z = (x.z + de[2]) * sc + se[2];
    x.w = (x.w + de[3]) * sc + se[3];
    *(float4*)(out + (size_t)b * 1024 + n) = x;
  }
}

// ---------------------------------------------------------------------------
extern "C" void kernel_launch(void* const* d_in, const int* in_sizes, int n_in,
                              void* d_out, int out_size, void* d_ws, size_t ws_size,
                              hipStream_t stream)
{
  const float* states     = (const float*)d_in[0];
  // d_in[1] (mask) is redundant: mask[b][t] == (t < lengths[b])
  const int* lengths      = (const int*)d_in[2];
  const int* boundaries   = (const int*)d_in[3];
  const int* leaf_order   = (const int*)d_in[4];
  const int* active       = (const int*)d_in[5];
  const int* is_leaf      = (const int*)d_in[6];
  const int* left_child   = (const int*)d_in[7];
  const int* right_child  = (const int*)d_in[8];
  const int* depth        = (const int*)d_in[9];
  const float* W1  = (const float*)d_in[10];
  const float* b1  = (const float*)d_in[11];
  const float* W2  = (const float*)d_in[12];
  const float* b2  = (const float*)d_in[13];
  const float* Wm1 = (const float*)d_in[14];
  const float* bm1 = (const float*)d_in[15];
  const float* Wm2 = (const float*)d_in[16];
  const float* bm2 = (const float*)d_in[17];
  const float* dembed = (const float*)d_in[18];
  const float* sembed = (const float*)d_in[19];
  float* out = (float*)d_out;

  // workspace layout (floats). Partials need no zero-init: every z-slice is
  // fully written before it is read (within the same launch, across a grid
  // barrier). Only barcnt + pooled need zeroing.
  unsigned* barcnt = (unsigned*)d_ws;            // 64 uints (256 B, padded)
  float* pooled = (float*)d_ws + 64;             // 256*1024
  float* P1 = pooled + 256 * 1024;               // 4*256*1024
  float* P2 = P1 + 4 * 256 * 1024;               // 4*256*1024
  float* P3 = P2 + 4 * 256 * 1024;               // 8*128*1024
  float* P4 = P3 + 8 * 128 * 1024;               // 8*128*1024
  float* P5 = P4 + 8 * 128 * 1024;               // 16*64*1024
  float* P6 = P5 + 16 * 64 * 1024;               // 16*64*1024

  hipMemsetAsync(d_ws, 0, (size_t)(64 + 256 * 1024) * sizeof(float), stream);

  fused_kernel<<<dim3(NBLK), dim3(256), 0, stream>>>(
      states, boundaries, lengths, leaf_order, active, is_leaf,
      left_child, right_child, depth,
      W1, b1, W2, b2, Wm1, bm1, Wm2, bm2, dembed, sembed,
      pooled, P1, P2, P3, P4, P5, P6, barcnt, out);
}